// Round 1
// baseline (276.908 us; speedup 1.0000x reference)
//
#include <hip/hip_runtime.h>
#include <hip/hip_bf16.h>
#include <stdint.h>

#define T_SZ 2048
#define B_SZ 64
#define H_SZ 256
#define I_SZ 256
#define M_SZ (B_SZ * T_SZ)          // 131072
#define TBH  (T_SZ * B_SZ * H_SZ)   // 33554432

typedef float f32x4 __attribute__((ext_vector_type(4)));
typedef short s16x8 __attribute__((ext_vector_type(8)));

// RTNE fp32 -> bf16 pair packed into one u32 (low = a, high = b)
__device__ __forceinline__ unsigned pack_bf16(float a, float b) {
    unsigned ua = __float_as_uint(a);
    unsigned ub = __float_as_uint(b);
    ua += 0x7fffu + ((ua >> 16) & 1u);
    ub += 0x7fffu + ((ub >> 16) & 1u);
    return (ua >> 16) | (ub & 0xffff0000u);
}

// async 16B global -> LDS (wave-uniform LDS base, lane writes base + lane*16)
__device__ __forceinline__ void gload_lds16(const unsigned short* g, unsigned short* l) {
    __builtin_amdgcn_global_load_lds(
        (const __attribute__((address_space(1))) unsigned int*)g,
        (__attribute__((address_space(3))) unsigned int*)l,
        16, 0, 0);
}

// ---------------------------------------------------------------------------
// prep: gb[b,h] = sum_j h0[b,j]*W_fh[h,j] + b_fi[h] + b_fh[h]
//       + convert W_fi (fp32 HxI) -> bf16 into Wb
// grid 64 blocks x 256 threads
// ---------------------------------------------------------------------------
__global__ void prep_kernel(const float* __restrict__ h0,
                            const float* __restrict__ W_fi,
                            const float* __restrict__ b_fi,
                            const float* __restrict__ W_fh,
                            const float* __restrict__ b_fh,
                            unsigned short* __restrict__ Wb,
                            float* __restrict__ gb) {
    __shared__ float h0s[H_SZ];
    const int b = blockIdx.x;
    const int h = threadIdx.x;
    h0s[h] = h0[b * H_SZ + h];
    __syncthreads();
    const float4* w4 = (const float4*)(W_fh + (size_t)h * H_SZ);
    float acc = 0.f;
#pragma unroll 8
    for (int j = 0; j < H_SZ / 4; ++j) {
        float4 w = w4[j];
        acc = fmaf(w.x, h0s[4 * j + 0], acc);
        acc = fmaf(w.y, h0s[4 * j + 1], acc);
        acc = fmaf(w.z, h0s[4 * j + 2], acc);
        acc = fmaf(w.w, h0s[4 * j + 3], acc);
    }
    gb[b * H_SZ + h] = acc + b_fi[h] + b_fh[h];

    // convert 4 W_fi elements per thread: 64*256*4 = 65536 total
    const int e = (b * 256 + h) * 4;
    float4 wv = *(const float4*)(W_fi + e);
    uint2 pk;
    pk.x = pack_bf16(wv.x, wv.y);
    pk.y = pack_bf16(wv.z, wv.w);
    *(uint2*)(Wb + e) = pk;
}

// ---------------------------------------------------------------------------
// main: gx = x @ W_fi^T as bf16 MFMA GEMM (M=131072, N=256, K=256),
// fused epilogue: g = gx + gb; s=sigmoid(g); m=tanh(g); c=s*(c0+m);
// h=s*tanh(c); out[t,b,h]=h; last-step h,c appended.
// 128x128 block tile, 4 waves of 64x64, BK=32, 8 K-iters.
// ---------------------------------------------------------------------------
__global__ __launch_bounds__(256) void lstm_main(
    const float* __restrict__ x,
    const unsigned short* __restrict__ Wb,
    const float* __restrict__ gb,
    const float* __restrict__ c0,
    float* __restrict__ out) {
    __shared__ __align__(16) unsigned short As[128 * 32];  // [m][k] k-contig
    __shared__ __align__(16) unsigned short Bs[128 * 32];  // [n][k] k-contig (W rows)

    const int tid  = threadIdx.x;
    const int lane = tid & 63;
    const int wid  = tid >> 6;
    const int bid  = blockIdx.x;
    const int mt = bid >> 1, nt = bid & 1;
    const int m0 = mt * 128, n0 = nt * 128;
    const int wm = (wid & 1) * 64, wn = (wid >> 1) * 64;

    f32x4 acc[4][4];
#pragma unroll
    for (int mi = 0; mi < 4; ++mi)
#pragma unroll
        for (int ni = 0; ni < 4; ++ni)
            acc[mi][ni] = (f32x4){0.f, 0.f, 0.f, 0.f};

    // A staging: slot = w*256 + tid, m = slot>>2, q = slot&3 (q = 8-float chunk)
    const int am = tid >> 2, aq = tid & 3;
    const float* aptr0 = x + (size_t)(m0 + am) * I_SZ + aq * 8;
    const float* aptr1 = aptr0 + (size_t)64 * I_SZ;

    // B staging slots (per-wave, 2 issues): slot = w*256 + wid*64 + lane
    const int bslot0 = wid * 64 + lane;
    const int bslot1 = 256 + bslot0;
    const int br0 = bslot0 >> 2, bq0 = bslot0 & 3;
    const int br1 = bslot1 >> 2, bq1 = bslot1 & 3;
    const unsigned short* bsrc0 = Wb + (size_t)(n0 + br0) * I_SZ + bq0 * 8;
    const unsigned short* bsrc1 = Wb + (size_t)(n0 + br1) * I_SZ + bq1 * 8;
    unsigned short* bdst0 = Bs + (size_t)(wid * 64) * 8;        // wave-uniform
    unsigned short* bdst1 = Bs + (size_t)(256 + wid * 64) * 8;  // wave-uniform

    const int fr = lane & 15;  // fragment row/col within 16
    const int fq = lane >> 4;  // quad

    for (int kt = 0; kt < 8; ++kt) {
        const int kof = kt * 32;
        if (kt) __syncthreads();  // protect LDS from overwrite

        // A global loads (fp32)
        const float4* p0 = (const float4*)(aptr0 + kof);
        const float4* p1 = (const float4*)(aptr1 + kof);
        float4 v0 = p0[0], v1 = p0[1];
        float4 v2 = p1[0], v3 = p1[1];

        // B async global->LDS (bf16, L2-hot)
        gload_lds16(bsrc0 + kof, bdst0);
        gload_lds16(bsrc1 + kof, bdst1);

        // A convert + LDS write (2 x ds_write_b128)
        uint4 pa, pb;
        pa.x = pack_bf16(v0.x, v0.y); pa.y = pack_bf16(v0.z, v0.w);
        pa.z = pack_bf16(v1.x, v1.y); pa.w = pack_bf16(v1.z, v1.w);
        pb.x = pack_bf16(v2.x, v2.y); pb.y = pack_bf16(v2.z, v2.w);
        pb.z = pack_bf16(v3.x, v3.y); pb.w = pack_bf16(v3.z, v3.w);
        *(uint4*)(As + (size_t)tid * 8) = pa;
        *(uint4*)(As + (size_t)(256 + tid) * 8) = pb;

        __syncthreads();  // drains vmcnt (global_load_lds) + lgkmcnt

        s16x8 af[4], bf[4];
#pragma unroll
        for (int mi = 0; mi < 4; ++mi)
            af[mi] = *(const s16x8*)(As + (wm + mi * 16 + fr) * 32 + fq * 8);
#pragma unroll
        for (int ni = 0; ni < 4; ++ni)
            bf[ni] = *(const s16x8*)(Bs + (wn + ni * 16 + fr) * 32 + fq * 8);
#pragma unroll
        for (int mi = 0; mi < 4; ++mi)
#pragma unroll
            for (int ni = 0; ni < 4; ++ni)
                acc[mi][ni] = __builtin_amdgcn_mfma_f32_16x16x32_bf16(
                    af[mi], bf[ni], acc[mi][ni], 0, 0, 0);
    }

    // Epilogue: C/D layout col = lane&15, row = (lane>>4)*4 + reg
    const int coln = n0 + wn + fr;
#pragma unroll
    for (int mi = 0; mi < 4; ++mi) {
#pragma unroll
        for (int r = 0; r < 4; ++r) {
            const int Mg = m0 + wm + mi * 16 + fq * 4 + r;
            const int bb = Mg >> 11;           // / T
            const int tt = Mg & (T_SZ - 1);    // % T
            const int obase = tt * (B_SZ * H_SZ) + bb * H_SZ;
            const float* gbrow = gb + bb * H_SZ;
            const float* c0row = c0 + bb * H_SZ;
            const bool last = (tt == T_SZ - 1);
#pragma unroll
            for (int ni = 0; ni < 4; ++ni) {
                const int h = coln + ni * 16;
                float g = acc[mi][ni][r] + gbrow[h];
                float gc = fminf(15.f, fmaxf(-15.f, g));
                float e = __expf(-gc);
                float s = __builtin_amdgcn_rcpf(1.f + e);        // sigmoid(g)
                float e2 = e * e;
                float m = (1.f - e2) * __builtin_amdgcn_rcpf(1.f + e2);  // tanh(g)
                float cv = s * (c0row[h] + m);
                float cc = fminf(15.f, fmaxf(-15.f, cv));
                float ec = __expf(-2.f * cc);
                float th = (1.f - ec) * __builtin_amdgcn_rcpf(1.f + ec); // tanh(c)
                float hv = s * th;
                out[obase + h] = hv;
                if (last) {
                    out[TBH + bb * H_SZ + h] = hv;                 // h_last
                    out[TBH + B_SZ * H_SZ + bb * H_SZ + h] = cv;   // c_last
                }
            }
        }
    }
}

extern "C" void kernel_launch(void* const* d_in, const int* in_sizes, int n_in,
                              void* d_out, int out_size, void* d_ws, size_t ws_size,
                              hipStream_t stream) {
    const float* x    = (const float*)d_in[0];
    const float* h0   = (const float*)d_in[1];
    const float* c0   = (const float*)d_in[2];
    const float* W_fi = (const float*)d_in[3];
    const float* b_fi = (const float*)d_in[4];
    const float* W_fh = (const float*)d_in[5];
    const float* b_fh = (const float*)d_in[6];
    float* out = (float*)d_out;

    unsigned short* Wb = (unsigned short*)d_ws;               // 65536 bf16 = 128 KB
    float* gb = (float*)((char*)d_ws + 131072);               // 16384 fp32 = 64 KB

    hipLaunchKernelGGL(prep_kernel, dim3(B_SZ), dim3(H_SZ), 0, stream,
                       h0, W_fi, b_fi, W_fh, b_fh, Wb, gb);
    hipLaunchKernelGGL(lstm_main, dim3(M_SZ / 128 * 2), dim3(256), 0, stream,
                       x, Wb, gb, c0, out);
}